// Round 6
// baseline (697.311 us; speedup 1.0000x reference)
//
#include <hip/hip_runtime.h>
#include <math.h>

// MARN cell, B=4096, IN_DIM=128, UNITS=256, NUM_K=64, NUM_S=256 (all fp32)
// Outputs flat: h (4096x256), c (4096x256), M (4096x64x256), k (4096x256)

#define BATCH 4096
#define INDIM 128
#define UNITS 256
#define NUMK  64
#define NUMS  256

typedef unsigned short u16;
typedef __attribute__((ext_vector_type(4))) float  f32x4;
typedef __attribute__((ext_vector_type(8))) short  s16x8;   // 8 bf16 (4 VGPRs) MFMA frag
typedef __attribute__((ext_vector_type(4))) u16    u16x4;
typedef __attribute__((ext_vector_type(8))) u16    u16x8;

__device__ __forceinline__ float sigf(float x) { return 1.0f / (1.0f + expf(-x)); }

// round-to-nearest-even f32 -> bf16 bits
__device__ __forceinline__ u16 f2bf(float x) {
    unsigned u = __float_as_uint(x);
    return (u16)((u + 0x7fffu + ((u >> 16) & 1u)) >> 16);
}
__device__ __forceinline__ float bf2f(u16 h) {
    return __uint_as_float(((unsigned)h) << 16);
}
__device__ __forceinline__ void split_bf(float x, u16& hi, u16& lo) {
    hi = f2bf(x);
    lo = f2bf(x - bf2f(hi));
}

// ---------------------------------------------------------------------------
// prep_a1: xh = [X | h_prev] -> bf16 hi/lo [4096][384]
// ---------------------------------------------------------------------------
__global__ __launch_bounds__(256) void prep_a1(
    const float* __restrict__ X, const float* __restrict__ hp,
    u16* __restrict__ Ahi, u16* __restrict__ Alo)
{
    const int idx = blockIdx.x * 256 + threadIdx.x;   // 4096*96 groups
    const int row = idx / 96;
    const int cg  = (idx - row * 96) * 4;
    float4 v;
    if (cg < INDIM) v = *(const float4*)(X + row * INDIM + cg);
    else            v = *(const float4*)(hp + row * UNITS + (cg - INDIM));
    u16x4 h, l;
    u16 th, tl;
    split_bf(v.x, th, tl); h.x = th; l.x = tl;
    split_bf(v.y, th, tl); h.y = th; l.y = tl;
    split_bf(v.z, th, tl); h.z = th; l.z = tl;
    split_bf(v.w, th, tl); h.w = th; l.w = tl;
    *(u16x4*)(Ahi + row * 384 + cg) = h;
    *(u16x4*)(Alo + row * 384 + cg) = l;
}

// ---------------------------------------------------------------------------
// pack_all: one dispatch packs W1t [1024][384], W3t [512][512], W4t [768][256]
// blockIdx 0..191 -> W1 ; 192..319 -> W3 ; 320..415 -> W4
// ---------------------------------------------------------------------------
__global__ __launch_bounds__(256) void pack_all(
    const float* __restrict__ Wf, const float* __restrict__ Wt,
    const float* __restrict__ Wi, const float* __restrict__ Wo,
    const float* __restrict__ Wr, const float* __restrict__ Wc,
    const float* __restrict__ Wh,
    const float* __restrict__ Wk, const float* __restrict__ We,
    const float* __restrict__ Wa,
    u16* __restrict__ W1hi, u16* __restrict__ W1lo,
    u16* __restrict__ W3hi, u16* __restrict__ W3lo,
    u16* __restrict__ W4hi, u16* __restrict__ W4lo)
{
    const int bid = blockIdx.x;
    if (bid < 192) {
        const int tid = bid * 256 + threadIdx.x;      // 1024*48
        const int n  = tid / 48;
        const int k0 = (tid - n * 48) * 8;
        const float* src = (n < 256) ? Wf : (n < 512) ? Wt : (n < 768) ? Wi : Wo;
        const int nc = n & 255;
        u16x8 h, l;
        #pragma unroll
        for (int j = 0; j < 8; ++j) {
            float x = src[(k0 + j) * 256 + nc];
            u16 th, tl;
            split_bf(x, th, tl);
            h[j] = th; l[j] = tl;
        }
        *(u16x8*)(W1hi + n * 384 + k0) = h;
        *(u16x8*)(W1lo + n * 384 + k0) = l;
    } else if (bid < 320) {
        const int tid = (bid - 192) * 256 + threadIdx.x;  // 512*64
        const int n  = tid / 64;
        const int k0 = (tid - n * 64) * 8;
        u16x8 h, l;
        #pragma unroll
        for (int j = 0; j < 8; ++j) {
            const int k = k0 + j;
            float x;
            if (n < 256) x = (k < 256) ? Wr[k * 256 + n] : Wc[(k - 256) * 256 + n];
            else         x = (k < 256) ? Wh[k * 256 + (n - 256)] : 0.0f;
            u16 th, tl;
            split_bf(x, th, tl);
            h[j] = th; l[j] = tl;
        }
        *(u16x8*)(W3hi + n * 512 + k0) = h;
        *(u16x8*)(W3lo + n * 512 + k0) = l;
    } else {
        const int tid = (bid - 320) * 256 + threadIdx.x;  // 768*32
        const int n  = tid / 32;
        const int k0 = (tid - n * 32) * 8;
        const float* src = (n < 256) ? Wk : (n < 512) ? We : Wa;
        const int nc = n & 255;
        u16x8 h, l;
        #pragma unroll
        for (int j = 0; j < 8; ++j) {
            float x = src[(k0 + j) * 256 + nc];
            u16 th, tl;
            split_bf(x, th, tl);
            h[j] = th; l[j] = tl;
        }
        *(u16x8*)(W4hi + n * 256 + k0) = h;
        *(u16x8*)(W4lo + n * 256 + k0) = l;
    }
}

// ---------------------------------------------------------------------------
// gemm1_e1: gates = xh @ W1 ; c = sig(f)*c_prev + sig(i)*sig(t); o stashed;
// c also written as bf16 hi/lo into A3 c-half. Fused epilogue: block owns
// 64 rows x 16 unit-cols x ALL 4 gates (j = gate, B row = j*256 + col).
// grid (64,16), 256 thr = 4 waves, wave tile 16 rows x 16 cols x 4 gates.
// ---------------------------------------------------------------------------
__global__ __launch_bounds__(256) void gemm1_e1(
    const u16* __restrict__ Ahi, const u16* __restrict__ Alo,
    const u16* __restrict__ Bhi, const u16* __restrict__ Blo,
    const float* __restrict__ c_prev,
    const float* __restrict__ bf, const float* __restrict__ bt,
    const float* __restrict__ bi, const float* __restrict__ bo,
    float* __restrict__ c_out, float* __restrict__ o_ws,
    u16* __restrict__ A3hi, u16* __restrict__ A3lo)
{
    const int K = 384;
    const int t = threadIdx.x;
    const int wave = t >> 6, lane = t & 63;
    const int m0 = blockIdx.x * 64 + wave * 16;
    const int col0 = blockIdx.y * 16;
    const int r = lane & 15, g = lane >> 4;

    const u16* pAh = Ahi + (size_t)(m0 + r) * K + g * 8;
    const u16* pAl = Alo + (size_t)(m0 + r) * K + g * 8;
    const u16* pBh = Bhi + (size_t)(col0 + r) * K + g * 8;
    const u16* pBl = Blo + (size_t)(col0 + r) * K + g * 8;

    f32x4 acc[4];
    #pragma unroll
    for (int j = 0; j < 4; ++j) acc[j] = (f32x4){0.f, 0.f, 0.f, 0.f};

    #pragma unroll 2
    for (int k0 = 0; k0 < 384; k0 += 32) {
        s16x8 ah = *(const s16x8*)(pAh + k0);
        s16x8 al = *(const s16x8*)(pAl + k0);
        #pragma unroll
        for (int j = 0; j < 4; ++j) {
            s16x8 bh = *(const s16x8*)(pBh + (size_t)j * 256 * K + k0);
            s16x8 bl = *(const s16x8*)(pBl + (size_t)j * 256 * K + k0);
            acc[j] = __builtin_amdgcn_mfma_f32_16x16x32_bf16(ah, bh, acc[j], 0, 0, 0);
            acc[j] = __builtin_amdgcn_mfma_f32_16x16x32_bf16(al, bh, acc[j], 0, 0, 0);
            acc[j] = __builtin_amdgcn_mfma_f32_16x16x32_bf16(ah, bl, acc[j], 0, 0, 0);
        }
    }

    const int col = col0 + r;
    const float bfv = bf[col], btv = bt[col], biv = bi[col], bov = bo[col];
    #pragma unroll
    for (int rr = 0; rr < 4; ++rr) {
        const int row = m0 + g * 4 + rr;
        const float cp = c_prev[(size_t)row * 256 + col];
        const float f  = sigf(acc[0][rr] + bfv);
        const float tt = sigf(acc[1][rr] + btv);
        const float i  = sigf(acc[2][rr] + biv);
        const float o  = sigf(acc[3][rr] + bov);
        const float cv = f * cp + i * tt;
        c_out[(size_t)row * 256 + col] = cv;
        o_ws [(size_t)row * 256 + col] = o;
        u16 hi, lo;
        split_bf(cv, hi, lo);
        A3hi[(size_t)row * 512 + 256 + col] = hi;
        A3lo[(size_t)row * 512 + 256 + col] = lo;
    }
}

// ---------------------------------------------------------------------------
// K2: cos -> softmax(alpha) -> r (bf16 hi/lo into A3 r-half).
// One block per batch row. Regular loads (keep M resident in L3 for k5).
// ---------------------------------------------------------------------------
__global__ __launch_bounds__(256) void k2_cosr(
    const float* __restrict__ M, const float* __restrict__ k_prev,
    float* __restrict__ alpha_out, u16* __restrict__ A3hi, u16* __restrict__ A3lo)
{
    const int b = blockIdx.x;
    const int t = threadIdx.x;
    const int lane = t & 63;
    const int w = t >> 6;

    __shared__ float sdot[64][8];
    __shared__ float sssq[64][8];
    __shared__ float salpha[64];
    __shared__ float spr[4][256];

    const float4 k4 = *(const float4*)(k_prev + b * NUMS + lane * 4);
    float kss = k4.x * k4.x + k4.y * k4.y + k4.z * k4.z + k4.w * k4.w;
    #pragma unroll
    for (int m = 1; m < 64; m <<= 1) kss += __shfl_xor(kss, m, 64);
    const float knorm = sqrtf(fmaxf(kss, 1e-12f));

    const float* Mb = M + (size_t)b * (NUMK * NUMS);
    f32x4 mreg[16];
    #pragma unroll
    for (int j = 0; j < 16; ++j)
        mreg[j] = *(const f32x4*)(Mb + (w * 16 + j) * NUMS + lane * 4);

    #pragma unroll
    for (int j = 0; j < 16; ++j) {
        const f32x4 m4 = mreg[j];
        float dot = m4.x * k4.x + m4.y * k4.y + m4.z * k4.z + m4.w * k4.w;
        float ssq = m4.x * m4.x + m4.y * m4.y + m4.z * m4.z + m4.w * m4.w;
        #pragma unroll
        for (int m = 1; m < 8; m <<= 1) {      // 3-step: 8-lane partials
            dot += __shfl_xor(dot, m, 64);
            ssq += __shfl_xor(ssq, m, 64);
        }
        if ((lane & 7) == 0) {
            sdot[w * 16 + j][lane >> 3] = dot;
            sssq[w * 16 + j][lane >> 3] = ssq;
        }
    }
    __syncthreads();

    if (t < 64) {
        float dot = 0.f, ssq = 0.f;
        #pragma unroll
        for (int q = 0; q < 8; ++q) { dot += sdot[t][q]; ssq += sssq[t][q]; }
        const float cosv = dot / (sqrtf(fmaxf(ssq, 1e-12f)) * knorm);
        float v = -cosv;
        float vmax = v;
        #pragma unroll
        for (int m = 1; m < 64; m <<= 1) vmax = fmaxf(vmax, __shfl_xor(vmax, m, 64));
        float e = expf(v - vmax);
        float s = e;
        #pragma unroll
        for (int m = 1; m < 64; m <<= 1) s += __shfl_xor(s, m, 64);
        const float al = e / s;
        salpha[t] = al;
        alpha_out[b * NUMK + t] = al;
    }
    __syncthreads();

    float pr0 = 0.f, pr1 = 0.f, pr2 = 0.f, pr3 = 0.f;
    #pragma unroll
    for (int j = 0; j < 16; ++j) {
        const float al = salpha[w * 16 + j];
        pr0 = fmaf(al, mreg[j].x, pr0);
        pr1 = fmaf(al, mreg[j].y, pr1);
        pr2 = fmaf(al, mreg[j].z, pr2);
        pr3 = fmaf(al, mreg[j].w, pr3);
    }
    *(float4*)&spr[w][lane * 4] = make_float4(pr0, pr1, pr2, pr3);
    __syncthreads();
    const float rv = spr[0][t] + spr[1][t] + spr[2][t] + spr[3][t];
    u16 hi, lo;
    split_bf(rv, hi, lo);
    A3hi[(size_t)b * 512 + t] = hi;
    A3lo[(size_t)b * 512 + t] = lo;
}

// ---------------------------------------------------------------------------
// gemm3_e2: [r|c] @ W3 ; h = o * tanh(c + sig(rc)*rh); h -> A4 bf16 hi/lo.
// j=0 -> rc (B row col), j=1 -> rh (B row 256+col). grid (64,16).
// ---------------------------------------------------------------------------
__global__ __launch_bounds__(256) void gemm3_e2(
    const u16* __restrict__ Ahi, const u16* __restrict__ Alo,
    const u16* __restrict__ Bhi, const u16* __restrict__ Blo,
    const float* __restrict__ c, const float* __restrict__ o,
    float* __restrict__ h_out, u16* __restrict__ A4hi, u16* __restrict__ A4lo)
{
    const int K = 512;
    const int t = threadIdx.x;
    const int wave = t >> 6, lane = t & 63;
    const int m0 = blockIdx.x * 64 + wave * 16;
    const int col0 = blockIdx.y * 16;
    const int r = lane & 15, g = lane >> 4;

    const u16* pAh = Ahi + (size_t)(m0 + r) * K + g * 8;
    const u16* pAl = Alo + (size_t)(m0 + r) * K + g * 8;
    const u16* pBh = Bhi + (size_t)(col0 + r) * K + g * 8;
    const u16* pBl = Blo + (size_t)(col0 + r) * K + g * 8;

    f32x4 acc[2];
    acc[0] = (f32x4){0.f, 0.f, 0.f, 0.f};
    acc[1] = (f32x4){0.f, 0.f, 0.f, 0.f};

    #pragma unroll 2
    for (int k0 = 0; k0 < 512; k0 += 32) {
        s16x8 ah = *(const s16x8*)(pAh + k0);
        s16x8 al = *(const s16x8*)(pAl + k0);
        #pragma unroll
        for (int j = 0; j < 2; ++j) {
            s16x8 bh = *(const s16x8*)(pBh + (size_t)j * 256 * K + k0);
            s16x8 bl = *(const s16x8*)(pBl + (size_t)j * 256 * K + k0);
            acc[j] = __builtin_amdgcn_mfma_f32_16x16x32_bf16(ah, bh, acc[j], 0, 0, 0);
            acc[j] = __builtin_amdgcn_mfma_f32_16x16x32_bf16(al, bh, acc[j], 0, 0, 0);
            acc[j] = __builtin_amdgcn_mfma_f32_16x16x32_bf16(ah, bl, acc[j], 0, 0, 0);
        }
    }

    const int col = col0 + r;
    #pragma unroll
    for (int rr = 0; rr < 4; ++rr) {
        const int row = m0 + g * 4 + rr;
        const float cv = c[(size_t)row * 256 + col];
        const float ov = o[(size_t)row * 256 + col];
        const float hv = ov * tanhf(cv + sigf(acc[0][rr]) * acc[1][rr]);
        h_out[(size_t)row * 256 + col] = hv;
        u16 hi, lo;
        split_bf(hv, hi, lo);
        A4hi[(size_t)row * 256 + col] = hi;
        A4lo[(size_t)row * 256 + col] = lo;
    }
}

// ---------------------------------------------------------------------------
// gemm4_e3: h @ {Wk,We,Wa} ; k = tanh(+bk), e = sig(+be), a = tanh(+ba).
// j=0,1,2 -> Wk,We,Wa (B row j*256+col). grid (64,16).
// ---------------------------------------------------------------------------
__global__ __launch_bounds__(256) void gemm4_e3(
    const u16* __restrict__ Ahi, const u16* __restrict__ Alo,
    const u16* __restrict__ Bhi, const u16* __restrict__ Blo,
    const float* __restrict__ bk, const float* __restrict__ be,
    const float* __restrict__ ba,
    float* __restrict__ k_out, float* __restrict__ e_ws, float* __restrict__ a_ws)
{
    const int K = 256;
    const int t = threadIdx.x;
    const int wave = t >> 6, lane = t & 63;
    const int m0 = blockIdx.x * 64 + wave * 16;
    const int col0 = blockIdx.y * 16;
    const int r = lane & 15, g = lane >> 4;

    const u16* pAh = Ahi + (size_t)(m0 + r) * K + g * 8;
    const u16* pAl = Alo + (size_t)(m0 + r) * K + g * 8;
    const u16* pBh = Bhi + (size_t)(col0 + r) * K + g * 8;
    const u16* pBl = Blo + (size_t)(col0 + r) * K + g * 8;

    f32x4 acc[3];
    #pragma unroll
    for (int j = 0; j < 3; ++j) acc[j] = (f32x4){0.f, 0.f, 0.f, 0.f};

    #pragma unroll 2
    for (int k0 = 0; k0 < 256; k0 += 32) {
        s16x8 ah = *(const s16x8*)(pAh + k0);
        s16x8 al = *(const s16x8*)(pAl + k0);
        #pragma unroll
        for (int j = 0; j < 3; ++j) {
            s16x8 bh = *(const s16x8*)(pBh + (size_t)j * 256 * K + k0);
            s16x8 bl = *(const s16x8*)(pBl + (size_t)j * 256 * K + k0);
            acc[j] = __builtin_amdgcn_mfma_f32_16x16x32_bf16(ah, bh, acc[j], 0, 0, 0);
            acc[j] = __builtin_amdgcn_mfma_f32_16x16x32_bf16(al, bh, acc[j], 0, 0, 0);
            acc[j] = __builtin_amdgcn_mfma_f32_16x16x32_bf16(ah, bl, acc[j], 0, 0, 0);
        }
    }

    const int col = col0 + r;
    const float bkv = bk[col], bev = be[col], bav = ba[col];
    #pragma unroll
    for (int rr = 0; rr < 4; ++rr) {
        const int row = m0 + g * 4 + rr;
        k_out[(size_t)row * 256 + col] = tanhf(acc[0][rr] + bkv);
        e_ws [(size_t)row * 256 + col] = sigf (acc[1][rr] + bev);
        a_ws [(size_t)row * 256 + col] = tanhf(acc[2][rr] + bav);
    }
}

// ---------------------------------------------------------------------------
// K5: M_curr = M_prev*(1 - alpha*e) + alpha*a
// Regular M load (L3-hot from k2), NT store of M_out.
// ---------------------------------------------------------------------------
__global__ __launch_bounds__(256) void k5_mup(
    const float* __restrict__ M, const float* __restrict__ alpha,
    const float* __restrict__ e, const float* __restrict__ a,
    float* __restrict__ Mout)
{
    const int b = blockIdx.x;
    const int t = threadIdx.x;
    __shared__ float sal[64];
    if (t < 64) sal[t] = alpha[b * NUMK + t];

    const int s4 = (t & 63) * 4;
    const int kr = t >> 6;
    const float4 e4 = *(const float4*)(e + b * NUMS + s4);
    const float4 a4 = *(const float4*)(a + b * NUMS + s4);
    __syncthreads();

    const float* Mb = M + (size_t)b * (NUMK * NUMS);
    float* Ob = Mout + (size_t)b * (NUMK * NUMS);
    #pragma unroll
    for (int j = 0; j < 16; ++j) {
        const int k = j * 4 + kr;
        const float al = sal[k];
        f32x4 m4 = *(const f32x4*)(Mb + k * NUMS + s4);
        f32x4 o4;
        o4.x = m4.x * (1.0f - al * e4.x) + al * a4.x;
        o4.y = m4.y * (1.0f - al * e4.y) + al * a4.y;
        o4.z = m4.z * (1.0f - al * e4.z) + al * a4.z;
        o4.w = m4.w * (1.0f - al * e4.w) + al * a4.w;
        __builtin_nontemporal_store(o4, (f32x4*)(Ob + k * NUMS + s4));
    }
}

// ---------------------------------------------------------------------------
extern "C" void kernel_launch(void* const* d_in, const int* in_sizes, int n_in,
                              void* d_out, int out_size, void* d_ws, size_t ws_size,
                              hipStream_t stream)
{
    (void)in_sizes; (void)n_in; (void)out_size; (void)ws_size;

    const float* X      = (const float*)d_in[0];
    const float* h_prev = (const float*)d_in[1];
    const float* c_prev = (const float*)d_in[2];
    const float* M_prev = (const float*)d_in[3];
    const float* k_prev = (const float*)d_in[4];
    const float* Wf = (const float*)d_in[5];
    const float* Wt = (const float*)d_in[6];
    const float* Wi = (const float*)d_in[7];
    const float* Wo = (const float*)d_in[8];
    const float* bf = (const float*)d_in[9];
    const float* bt = (const float*)d_in[10];
    const float* bi = (const float*)d_in[11];
    const float* bo = (const float*)d_in[12];
    const float* Wk = (const float*)d_in[13];
    const float* bk = (const float*)d_in[14];
    const float* Wr = (const float*)d_in[15];
    const float* Wc = (const float*)d_in[16];
    const float* Wh = (const float*)d_in[17];
    const float* We = (const float*)d_in[18];
    const float* be = (const float*)d_in[19];
    const float* Wa = (const float*)d_in[20];
    const float* ba = (const float*)d_in[21];

    float* out = (float*)d_out;
    float* h_out = out;
    float* c_out = out + 1048576;
    float* M_out = out + 2097152;
    float* k_out = out + 69206016;

    // workspace carve-up (bytes, 256-aligned)
    char* w = (char*)d_ws;
    size_t off = 0;
    auto carve = [&](size_t bytes) { void* p = w + off; off += (bytes + 255) & ~(size_t)255; return p; };
    u16* A1hi = (u16*)carve(4096ull * 384 * 2);
    u16* A1lo = (u16*)carve(4096ull * 384 * 2);
    u16* W1hi = (u16*)carve(1024ull * 384 * 2);
    u16* W1lo = (u16*)carve(1024ull * 384 * 2);
    u16* W3hi = (u16*)carve(512ull * 512 * 2);
    u16* W3lo = (u16*)carve(512ull * 512 * 2);
    u16* W4hi = (u16*)carve(768ull * 256 * 2);
    u16* W4lo = (u16*)carve(768ull * 256 * 2);
    u16* A3hi = (u16*)carve(4096ull * 512 * 2);
    u16* A3lo = (u16*)carve(4096ull * 512 * 2);
    u16* A4hi = (u16*)carve(4096ull * 256 * 2);
    u16* A4lo = (u16*)carve(4096ull * 256 * 2);
    float* o_ws  = (float*)carve(4096ull * 256 * 4);
    float* al_ws = (float*)carve(4096ull * 64 * 4);
    float* e_ws  = (float*)carve(4096ull * 256 * 4);
    float* a_ws  = (float*)carve(4096ull * 256 * 4);

    // prep
    pack_all<<<416, 256, 0, stream>>>(Wf, Wt, Wi, Wo, Wr, Wc, Wh, Wk, We, Wa,
                                      W1hi, W1lo, W3hi, W3lo, W4hi, W4lo);
    prep_a1<<<1536, 256, 0, stream>>>(X, h_prev, A1hi, A1lo);

    // gates GEMM + fused epilogue -> c, o, A3 c-half
    gemm1_e1<<<dim3(64, 16), 256, 0, stream>>>(A1hi, A1lo, W1hi, W1lo, c_prev,
                                               bf, bt, bi, bo,
                                               c_out, o_ws, A3hi, A3lo);

    // cos/softmax/r -> A3 r-half (M read lands in L3, close to k5)
    k2_cosr<<<4096, 256, 0, stream>>>(M_prev, k_prev, al_ws, A3hi, A3lo);

    // [r|c] GEMM + fused epilogue -> h, A4
    gemm3_e2<<<dim3(64, 16), 256, 0, stream>>>(A3hi, A3lo, W3hi, W3lo,
                                               c_out, o_ws, h_out, A4hi, A4lo);

    // h GEMM + fused epilogue -> k_out, e, a
    gemm4_e3<<<dim3(64, 16), 256, 0, stream>>>(A4hi, A4lo, W4hi, W4lo,
                                               bk, be, ba, k_out, e_ws, a_ws);

    // M update
    k5_mup<<<4096, 256, 0, stream>>>(M_prev, al_ws, e_ws, a_ws, M_out);
}

// Round 7
// 681.947 us; speedup vs baseline: 1.0225x; 1.0225x over previous
//
#include <hip/hip_runtime.h>
#include <math.h>

// MARN cell, B=4096, IN_DIM=128, UNITS=256, NUM_K=64, NUM_S=256 (all fp32)
// Outputs flat: h (4096x256), c (4096x256), M (4096x64x256), k (4096x256)

#define BATCH 4096
#define INDIM 128
#define UNITS 256
#define NUMK  64
#define NUMS  256

typedef unsigned short u16;
typedef __attribute__((ext_vector_type(4))) float  f32x4;
typedef __attribute__((ext_vector_type(8))) short  s16x8;   // 8 bf16 (4 VGPRs) MFMA frag
typedef __attribute__((ext_vector_type(4))) u16    u16x4;
typedef __attribute__((ext_vector_type(8))) u16    u16x8;

__device__ __forceinline__ float sigf(float x) { return 1.0f / (1.0f + expf(-x)); }

// round-to-nearest-even f32 -> bf16 bits
__device__ __forceinline__ u16 f2bf(float x) {
    unsigned u = __float_as_uint(x);
    return (u16)((u + 0x7fffu + ((u >> 16) & 1u)) >> 16);
}
__device__ __forceinline__ float bf2f(u16 h) {
    return __uint_as_float(((unsigned)h) << 16);
}
__device__ __forceinline__ void split_bf(float x, u16& hi, u16& lo) {
    hi = f2bf(x);
    lo = f2bf(x - bf2f(hi));
}

// ---------------------------------------------------------------------------
// prep_all: blockIdx 0..1535 -> A1 (xh bf16 hi/lo); 1536..1727 -> W1;
//           1728..1855 -> W3; 1856..1951 -> W4
// ---------------------------------------------------------------------------
__global__ __launch_bounds__(256) void prep_all(
    const float* __restrict__ X, const float* __restrict__ hp,
    const float* __restrict__ Wf, const float* __restrict__ Wt,
    const float* __restrict__ Wi, const float* __restrict__ Wo,
    const float* __restrict__ Wr, const float* __restrict__ Wc,
    const float* __restrict__ Wh,
    const float* __restrict__ Wk, const float* __restrict__ We,
    const float* __restrict__ Wa,
    u16* __restrict__ A1hi, u16* __restrict__ A1lo,
    u16* __restrict__ W1hi, u16* __restrict__ W1lo,
    u16* __restrict__ W3hi, u16* __restrict__ W3lo,
    u16* __restrict__ W4hi, u16* __restrict__ W4lo)
{
    const int bid = blockIdx.x;
    if (bid < 1536) {
        const int idx = bid * 256 + threadIdx.x;   // 4096*96 groups
        const int row = idx / 96;
        const int cg  = (idx - row * 96) * 4;
        float4 v;
        if (cg < INDIM) v = *(const float4*)(X + row * INDIM + cg);
        else            v = *(const float4*)(hp + row * UNITS + (cg - INDIM));
        u16x4 h, l;
        u16 th, tl;
        split_bf(v.x, th, tl); h.x = th; l.x = tl;
        split_bf(v.y, th, tl); h.y = th; l.y = tl;
        split_bf(v.z, th, tl); h.z = th; l.z = tl;
        split_bf(v.w, th, tl); h.w = th; l.w = tl;
        *(u16x4*)(A1hi + row * 384 + cg) = h;
        *(u16x4*)(A1lo + row * 384 + cg) = l;
    } else if (bid < 1728) {
        const int tid = (bid - 1536) * 256 + threadIdx.x;  // 1024*48
        const int n  = tid / 48;
        const int k0 = (tid - n * 48) * 8;
        const float* src = (n < 256) ? Wf : (n < 512) ? Wt : (n < 768) ? Wi : Wo;
        const int nc = n & 255;
        u16x8 h, l;
        #pragma unroll
        for (int j = 0; j < 8; ++j) {
            float x = src[(k0 + j) * 256 + nc];
            u16 th, tl;
            split_bf(x, th, tl);
            h[j] = th; l[j] = tl;
        }
        *(u16x8*)(W1hi + n * 384 + k0) = h;
        *(u16x8*)(W1lo + n * 384 + k0) = l;
    } else if (bid < 1856) {
        const int tid = (bid - 1728) * 256 + threadIdx.x;  // 512*64
        const int n  = tid / 64;
        const int k0 = (tid - n * 64) * 8;
        u16x8 h, l;
        #pragma unroll
        for (int j = 0; j < 8; ++j) {
            const int k = k0 + j;
            float x;
            if (n < 256) x = (k < 256) ? Wr[k * 256 + n] : Wc[(k - 256) * 256 + n];
            else         x = (k < 256) ? Wh[k * 256 + (n - 256)] : 0.0f;
            u16 th, tl;
            split_bf(x, th, tl);
            h[j] = th; l[j] = tl;
        }
        *(u16x8*)(W3hi + n * 512 + k0) = h;
        *(u16x8*)(W3lo + n * 512 + k0) = l;
    } else {
        const int tid = (bid - 1856) * 256 + threadIdx.x;  // 768*32
        const int n  = tid / 32;
        const int k0 = (tid - n * 32) * 8;
        const float* src = (n < 256) ? Wk : (n < 512) ? We : Wa;
        const int nc = n & 255;
        u16x8 h, l;
        #pragma unroll
        for (int j = 0; j < 8; ++j) {
            float x = src[(k0 + j) * 256 + nc];
            u16 th, tl;
            split_bf(x, th, tl);
            h[j] = th; l[j] = tl;
        }
        *(u16x8*)(W4hi + n * 256 + k0) = h;
        *(u16x8*)(W4lo + n * 256 + k0) = l;
    }
}

// ---------------------------------------------------------------------------
// mega1: blocks 0..4095  -> k2 path: cos -> softmax(alpha) -> r (A3 r-half)
//        blocks 4096..5119 -> gemm1 path: gates GEMM + fused e1 (A3 c-half)
// k2 blocks first so the M-stream starts immediately; MFMA blocks fill in.
// Writes are disjoint; paths are data-independent.
// ---------------------------------------------------------------------------
__global__ __launch_bounds__(256) void mega1(
    const float* __restrict__ M, const float* __restrict__ k_prev,
    float* __restrict__ alpha_out,
    const u16* __restrict__ Ahi, const u16* __restrict__ Alo,
    const u16* __restrict__ Bhi, const u16* __restrict__ Blo,
    const float* __restrict__ c_prev,
    const float* __restrict__ bf, const float* __restrict__ bt,
    const float* __restrict__ bi, const float* __restrict__ bo,
    float* __restrict__ c_out, float* __restrict__ o_ws,
    u16* __restrict__ A3hi, u16* __restrict__ A3lo)
{
    const int t = threadIdx.x;
    if (blockIdx.x < 4096) {
        // ---------------- k2: cos/softmax/r ----------------
        const int b = blockIdx.x;
        const int lane = t & 63;
        const int w = t >> 6;

        __shared__ float sdot[64][8];
        __shared__ float sssq[64][8];
        __shared__ float salpha[64];
        __shared__ float spr[4][256];

        const float4 k4 = *(const float4*)(k_prev + b * NUMS + lane * 4);
        float kss = k4.x * k4.x + k4.y * k4.y + k4.z * k4.z + k4.w * k4.w;
        #pragma unroll
        for (int m = 1; m < 64; m <<= 1) kss += __shfl_xor(kss, m, 64);
        const float knorm = sqrtf(fmaxf(kss, 1e-12f));

        const float* Mb = M + (size_t)b * (NUMK * NUMS);
        f32x4 mreg[16];
        #pragma unroll
        for (int j = 0; j < 16; ++j)
            mreg[j] = *(const f32x4*)(Mb + (w * 16 + j) * NUMS + lane * 4);

        #pragma unroll
        for (int j = 0; j < 16; ++j) {
            const f32x4 m4 = mreg[j];
            float dot = m4.x * k4.x + m4.y * k4.y + m4.z * k4.z + m4.w * k4.w;
            float ssq = m4.x * m4.x + m4.y * m4.y + m4.z * m4.z + m4.w * m4.w;
            #pragma unroll
            for (int m = 1; m < 8; m <<= 1) {
                dot += __shfl_xor(dot, m, 64);
                ssq += __shfl_xor(ssq, m, 64);
            }
            if ((lane & 7) == 0) {
                sdot[w * 16 + j][lane >> 3] = dot;
                sssq[w * 16 + j][lane >> 3] = ssq;
            }
        }
        __syncthreads();

        if (t < 64) {
            float dot = 0.f, ssq = 0.f;
            #pragma unroll
            for (int q = 0; q < 8; ++q) { dot += sdot[t][q]; ssq += sssq[t][q]; }
            const float cosv = dot / (sqrtf(fmaxf(ssq, 1e-12f)) * knorm);
            float v = -cosv;
            float vmax = v;
            #pragma unroll
            for (int m = 1; m < 64; m <<= 1) vmax = fmaxf(vmax, __shfl_xor(vmax, m, 64));
            float e = expf(v - vmax);
            float s = e;
            #pragma unroll
            for (int m = 1; m < 64; m <<= 1) s += __shfl_xor(s, m, 64);
            const float al = e / s;
            salpha[t] = al;
            alpha_out[b * NUMK + t] = al;
        }
        __syncthreads();

        float pr0 = 0.f, pr1 = 0.f, pr2 = 0.f, pr3 = 0.f;
        #pragma unroll
        for (int j = 0; j < 16; ++j) {
            const float al = salpha[w * 16 + j];
            pr0 = fmaf(al, mreg[j].x, pr0);
            pr1 = fmaf(al, mreg[j].y, pr1);
            pr2 = fmaf(al, mreg[j].z, pr2);
            pr3 = fmaf(al, mreg[j].w, pr3);
        }
        *(float4*)&spr[w][lane * 4] = make_float4(pr0, pr1, pr2, pr3);
        __syncthreads();
        const float rv = spr[0][t] + spr[1][t] + spr[2][t] + spr[3][t];
        u16 hi, lo;
        split_bf(rv, hi, lo);
        A3hi[(size_t)b * 512 + t] = hi;
        A3lo[(size_t)b * 512 + t] = lo;
    } else {
        // ---------------- gemm1 + e1 ----------------
        const int K = 384;
        const int bid = blockIdx.x - 4096;       // 0..1023
        const int wave = t >> 6, lane = t & 63;
        const int m0 = (bid >> 4) * 64 + wave * 16;
        const int col0 = (bid & 15) * 16;
        const int r = lane & 15, g = lane >> 4;

        const u16* pAh = Ahi + (size_t)(m0 + r) * K + g * 8;
        const u16* pAl = Alo + (size_t)(m0 + r) * K + g * 8;
        const u16* pBh = Bhi + (size_t)(col0 + r) * K + g * 8;
        const u16* pBl = Blo + (size_t)(col0 + r) * K + g * 8;

        f32x4 acc[4];
        #pragma unroll
        for (int j = 0; j < 4; ++j) acc[j] = (f32x4){0.f, 0.f, 0.f, 0.f};

        #pragma unroll 2
        for (int k0 = 0; k0 < 384; k0 += 32) {
            s16x8 ah = *(const s16x8*)(pAh + k0);
            s16x8 al = *(const s16x8*)(pAl + k0);
            #pragma unroll
            for (int j = 0; j < 4; ++j) {
                s16x8 bh = *(const s16x8*)(pBh + (size_t)j * 256 * K + k0);
                s16x8 bl = *(const s16x8*)(pBl + (size_t)j * 256 * K + k0);
                acc[j] = __builtin_amdgcn_mfma_f32_16x16x32_bf16(ah, bh, acc[j], 0, 0, 0);
                acc[j] = __builtin_amdgcn_mfma_f32_16x16x32_bf16(al, bh, acc[j], 0, 0, 0);
                acc[j] = __builtin_amdgcn_mfma_f32_16x16x32_bf16(ah, bl, acc[j], 0, 0, 0);
            }
        }

        const int col = col0 + r;
        const float bfv = bf[col], btv = bt[col], biv = bi[col], bov = bo[col];
        #pragma unroll
        for (int rr = 0; rr < 4; ++rr) {
            const int row = m0 + g * 4 + rr;
            const float cp = c_prev[(size_t)row * 256 + col];
            const float f  = sigf(acc[0][rr] + bfv);
            const float tt = sigf(acc[1][rr] + btv);
            const float i  = sigf(acc[2][rr] + biv);
            const float o  = sigf(acc[3][rr] + bov);
            const float cv = f * cp + i * tt;
            c_out[(size_t)row * 256 + col] = cv;
            o_ws [(size_t)row * 256 + col] = o;
            u16 hi, lo;
            split_bf(cv, hi, lo);
            A3hi[(size_t)row * 512 + 256 + col] = hi;
            A3lo[(size_t)row * 512 + 256 + col] = lo;
        }
    }
}

// ---------------------------------------------------------------------------
// gemm3_e2: [r|c] @ W3 ; h = o * tanh(c + sig(rc)*rh); h -> A4 bf16 hi/lo.
// ---------------------------------------------------------------------------
__global__ __launch_bounds__(256) void gemm3_e2(
    const u16* __restrict__ Ahi, const u16* __restrict__ Alo,
    const u16* __restrict__ Bhi, const u16* __restrict__ Blo,
    const float* __restrict__ c, const float* __restrict__ o,
    float* __restrict__ h_out, u16* __restrict__ A4hi, u16* __restrict__ A4lo)
{
    const int K = 512;
    const int t = threadIdx.x;
    const int wave = t >> 6, lane = t & 63;
    const int m0 = blockIdx.x * 64 + wave * 16;
    const int col0 = blockIdx.y * 16;
    const int r = lane & 15, g = lane >> 4;

    const u16* pAh = Ahi + (size_t)(m0 + r) * K + g * 8;
    const u16* pAl = Alo + (size_t)(m0 + r) * K + g * 8;
    const u16* pBh = Bhi + (size_t)(col0 + r) * K + g * 8;
    const u16* pBl = Blo + (size_t)(col0 + r) * K + g * 8;

    f32x4 acc[2];
    acc[0] = (f32x4){0.f, 0.f, 0.f, 0.f};
    acc[1] = (f32x4){0.f, 0.f, 0.f, 0.f};

    #pragma unroll 2
    for (int k0 = 0; k0 < 512; k0 += 32) {
        s16x8 ah = *(const s16x8*)(pAh + k0);
        s16x8 al = *(const s16x8*)(pAl + k0);
        #pragma unroll
        for (int j = 0; j < 2; ++j) {
            s16x8 bh = *(const s16x8*)(pBh + (size_t)j * 256 * K + k0);
            s16x8 bl = *(const s16x8*)(pBl + (size_t)j * 256 * K + k0);
            acc[j] = __builtin_amdgcn_mfma_f32_16x16x32_bf16(ah, bh, acc[j], 0, 0, 0);
            acc[j] = __builtin_amdgcn_mfma_f32_16x16x32_bf16(al, bh, acc[j], 0, 0, 0);
            acc[j] = __builtin_amdgcn_mfma_f32_16x16x32_bf16(ah, bl, acc[j], 0, 0, 0);
        }
    }

    const int col = col0 + r;
    #pragma unroll
    for (int rr = 0; rr < 4; ++rr) {
        const int row = m0 + g * 4 + rr;
        const float cv = c[(size_t)row * 256 + col];
        const float ov = o[(size_t)row * 256 + col];
        const float hv = ov * tanhf(cv + sigf(acc[0][rr]) * acc[1][rr]);
        h_out[(size_t)row * 256 + col] = hv;
        u16 hi, lo;
        split_bf(hv, hi, lo);
        A4hi[(size_t)row * 256 + col] = hi;
        A4lo[(size_t)row * 256 + col] = lo;
    }
}

// ---------------------------------------------------------------------------
// gemm4_e3: h @ {Wk,We,Wa} ; k = tanh(+bk), e = sig(+be), a = tanh(+ba).
// ---------------------------------------------------------------------------
__global__ __launch_bounds__(256) void gemm4_e3(
    const u16* __restrict__ Ahi, const u16* __restrict__ Alo,
    const u16* __restrict__ Bhi, const u16* __restrict__ Blo,
    const float* __restrict__ bk, const float* __restrict__ be,
    const float* __restrict__ ba,
    float* __restrict__ k_out, float* __restrict__ e_ws, float* __restrict__ a_ws)
{
    const int K = 256;
    const int t = threadIdx.x;
    const int wave = t >> 6, lane = t & 63;
    const int m0 = blockIdx.x * 64 + wave * 16;
    const int col0 = blockIdx.y * 16;
    const int r = lane & 15, g = lane >> 4;

    const u16* pAh = Ahi + (size_t)(m0 + r) * K + g * 8;
    const u16* pAl = Alo + (size_t)(m0 + r) * K + g * 8;
    const u16* pBh = Bhi + (size_t)(col0 + r) * K + g * 8;
    const u16* pBl = Blo + (size_t)(col0 + r) * K + g * 8;

    f32x4 acc[3];
    #pragma unroll
    for (int j = 0; j < 3; ++j) acc[j] = (f32x4){0.f, 0.f, 0.f, 0.f};

    #pragma unroll 2
    for (int k0 = 0; k0 < 256; k0 += 32) {
        s16x8 ah = *(const s16x8*)(pAh + k0);
        s16x8 al = *(const s16x8*)(pAl + k0);
        #pragma unroll
        for (int j = 0; j < 3; ++j) {
            s16x8 bh = *(const s16x8*)(pBh + (size_t)j * 256 * K + k0);
            s16x8 bl = *(const s16x8*)(pBl + (size_t)j * 256 * K + k0);
            acc[j] = __builtin_amdgcn_mfma_f32_16x16x32_bf16(ah, bh, acc[j], 0, 0, 0);
            acc[j] = __builtin_amdgcn_mfma_f32_16x16x32_bf16(al, bh, acc[j], 0, 0, 0);
            acc[j] = __builtin_amdgcn_mfma_f32_16x16x32_bf16(ah, bl, acc[j], 0, 0, 0);
        }
    }

    const int col = col0 + r;
    const float bkv = bk[col], bev = be[col], bav = ba[col];
    #pragma unroll
    for (int rr = 0; rr < 4; ++rr) {
        const int row = m0 + g * 4 + rr;
        k_out[(size_t)row * 256 + col] = tanhf(acc[0][rr] + bkv);
        e_ws [(size_t)row * 256 + col] = sigf (acc[1][rr] + bev);
        a_ws [(size_t)row * 256 + col] = tanhf(acc[2][rr] + bav);
    }
}

// ---------------------------------------------------------------------------
// K5: M_curr = M_prev*(1 - alpha*e) + alpha*a
// REVERSED block order: k2 read M rows 0->4095; reading 4095->0 here turns
// the L3 LRU thrash into mostly-hits (MRU-first). NT store of M_out.
// ---------------------------------------------------------------------------
__global__ __launch_bounds__(256) void k5_mup(
    const float* __restrict__ M, const float* __restrict__ alpha,
    const float* __restrict__ e, const float* __restrict__ a,
    float* __restrict__ Mout)
{
    const int b = 4095 - blockIdx.x;
    const int t = threadIdx.x;
    __shared__ float sal[64];
    if (t < 64) sal[t] = alpha[b * NUMK + t];

    const int s4 = (t & 63) * 4;
    const int kr = t >> 6;
    const float4 e4 = *(const float4*)(e + b * NUMS + s4);
    const float4 a4 = *(const float4*)(a + b * NUMS + s4);
    __syncthreads();

    const float* Mb = M + (size_t)b * (NUMK * NUMS);
    float* Ob = Mout + (size_t)b * (NUMK * NUMS);
    #pragma unroll
    for (int j = 0; j < 16; ++j) {
        const int k = j * 4 + kr;
        const float al = sal[k];
        f32x4 m4 = *(const f32x4*)(Mb + k * NUMS + s4);
        f32x4 o4;
        o4.x = m4.x * (1.0f - al * e4.x) + al * a4.x;
        o4.y = m4.y * (1.0f - al * e4.y) + al * a4.y;
        o4.z = m4.z * (1.0f - al * e4.z) + al * a4.z;
        o4.w = m4.w * (1.0f - al * e4.w) + al * a4.w;
        __builtin_nontemporal_store(o4, (f32x4*)(Ob + k * NUMS + s4));
    }
}

// ---------------------------------------------------------------------------
extern "C" void kernel_launch(void* const* d_in, const int* in_sizes, int n_in,
                              void* d_out, int out_size, void* d_ws, size_t ws_size,
                              hipStream_t stream)
{
    (void)in_sizes; (void)n_in; (void)out_size; (void)ws_size;

    const float* X      = (const float*)d_in[0];
    const float* h_prev = (const float*)d_in[1];
    const float* c_prev = (const float*)d_in[2];
    const float* M_prev = (const float*)d_in[3];
    const float* k_prev = (const float*)d_in[4];
    const float* Wf = (const float*)d_in[5];
    const float* Wt = (const float*)d_in[6];
    const float* Wi = (const float*)d_in[7];
    const float* Wo = (const float*)d_in[8];
    const float* bf = (const float*)d_in[9];
    const float* bt = (const float*)d_in[10];
    const float* bi = (const float*)d_in[11];
    const float* bo = (const float*)d_in[12];
    const float* Wk = (const float*)d_in[13];
    const float* bk = (const float*)d_in[14];
    const float* Wr = (const float*)d_in[15];
    const float* Wc = (const float*)d_in[16];
    const float* Wh = (const float*)d_in[17];
    const float* We = (const float*)d_in[18];
    const float* be = (const float*)d_in[19];
    const float* Wa = (const float*)d_in[20];
    const float* ba = (const float*)d_in[21];

    float* out = (float*)d_out;
    float* h_out = out;
    float* c_out = out + 1048576;
    float* M_out = out + 2097152;
    float* k_out = out + 69206016;

    // workspace carve-up (bytes, 256-aligned)
    char* w = (char*)d_ws;
    size_t off = 0;
    auto carve = [&](size_t bytes) { void* p = w + off; off += (bytes + 255) & ~(size_t)255; return p; };
    u16* A1hi = (u16*)carve(4096ull * 384 * 2);
    u16* A1lo = (u16*)carve(4096ull * 384 * 2);
    u16* W1hi = (u16*)carve(1024ull * 384 * 2);
    u16* W1lo = (u16*)carve(1024ull * 384 * 2);
    u16* W3hi = (u16*)carve(512ull * 512 * 2);
    u16* W3lo = (u16*)carve(512ull * 512 * 2);
    u16* W4hi = (u16*)carve(768ull * 256 * 2);
    u16* W4lo = (u16*)carve(768ull * 256 * 2);
    u16* A3hi = (u16*)carve(4096ull * 512 * 2);
    u16* A3lo = (u16*)carve(4096ull * 512 * 2);
    u16* A4hi = (u16*)carve(4096ull * 256 * 2);
    u16* A4lo = (u16*)carve(4096ull * 256 * 2);
    float* o_ws  = (float*)carve(4096ull * 256 * 4);
    float* al_ws = (float*)carve(4096ull * 64 * 4);
    float* e_ws  = (float*)carve(4096ull * 256 * 4);
    float* a_ws  = (float*)carve(4096ull * 256 * 4);

    // prep: A1 pack + all weight packs in one dispatch
    prep_all<<<1952, 256, 0, stream>>>(X, h_prev, Wf, Wt, Wi, Wo, Wr, Wc, Wh,
                                       Wk, We, Wa,
                                       A1hi, A1lo, W1hi, W1lo, W3hi, W3lo, W4hi, W4lo);

    // k2 (M-stream) + gates GEMM concurrently (independent, disjoint writes)
    mega1<<<5120, 256, 0, stream>>>(M_prev, k_prev, al_ws,
                                    A1hi, A1lo, W1hi, W1lo, c_prev,
                                    bf, bt, bi, bo,
                                    c_out, o_ws, A3hi, A3lo);

    // [r|c] GEMM + fused epilogue -> h, A4
    gemm3_e2<<<dim3(64, 16), 256, 0, stream>>>(A3hi, A3lo, W3hi, W3lo,
                                               c_out, o_ws, h_out, A4hi, A4lo);

    // h GEMM + fused epilogue -> k_out, e, a
    gemm4_e3<<<dim3(64, 16), 256, 0, stream>>>(A4hi, A4lo, W4hi, W4lo,
                                               bk, be, ba, k_out, e_ws, a_ws);

    // M update (reversed order for L3 MRU hits on M_prev)
    k5_mup<<<4096, 256, 0, stream>>>(M_prev, al_ws, e_ws, a_ws, M_out);
}